// Round 8
// baseline (288.160 us; speedup 1.0000x reference)
//
#include <hip/hip_runtime.h>
#include <math.h>

typedef _Float16 f16x8 __attribute__((ext_vector_type(8)));
typedef float f32x16 __attribute__((ext_vector_type(16)));

#define N_PTS 32768
#define DIM 256
#define K_CODES 8192
#define NSTRIP 4
#define SCOLS 2048      // cols per strip
#define NCT 32          // 64-col tiles per strip

// ws byte offsets
#define WS_WNH     0           // 8192 f32
#define WS_COUNTS  32768       // 8192 i32
#define WS_LOSSP   65536       // 8192 f32
#define WS_PART    262144      // 4*32768 uint2 = 1 MB
#define WS_WT      2359296     // wT [8192][256] f32 = 8 MB
#define WS_BPK     10747904    // B panels: 4 strips * 128 panels * 8 KB = 4 MB

#define GLL(dst, src) __builtin_amdgcn_global_load_lds( \
    (const __attribute__((address_space(1))) void*)(src), \
    (__attribute__((address_space(3))) void*)(dst), 16, 0, 0)

// ---------------- wnorm/2 (fp64 accum, 4-way ILP), zero counts ----------------
__global__ void vq_prep(const float* __restrict__ w, float* __restrict__ wnh,
                        int* __restrict__ counts) {
    int k = blockIdx.x * 256 + threadIdx.x;
    double s0 = 0.0, s1 = 0.0, s2 = 0.0, s3 = 0.0;
    for (int d = 0; d < DIM; d += 4) {
        float a = w[(size_t)d * K_CODES + k];
        float b = w[(size_t)(d + 1) * K_CODES + k];
        float c = w[(size_t)(d + 2) * K_CODES + k];
        float e = w[(size_t)(d + 3) * K_CODES + k];
        s0 += (double)a * a; s1 += (double)b * b;
        s2 += (double)c * c; s3 += (double)e * e;
    }
    wnh[k] = (float)(0.5 * ((s0 + s1) + (s2 + s3)));
    counts[k] = 0;
}

// ---------------- pack w -> B panels (fp16, linear [k8][col] image) + wT ----------------
// panel p = strip*128 + ct*4 + kp: 8 KB; elem (col, k) at byte (k>>3)*1024 + col*16 + (k&7)*2
__global__ void vq_prep_w(const float* __restrict__ w, char* __restrict__ Bpk,
                          float* __restrict__ wT) {
    __shared__ float t[64][129];
    int tid = threadIdx.x;
    int ct128 = blockIdx.x >> 2, ks4 = blockIdx.x & 3;
    int k0 = ks4 * 64, n0 = ct128 * 128;
    for (int i = 0; i < 32; ++i) {
        int idx = i * 256 + tid;
        int kk = idx >> 7, nn = idx & 127;
        t[kk][nn] = w[(size_t)(k0 + kk) * K_CODES + n0 + nn];
    }
    __syncthreads();
    for (int i = 0; i < 4; ++i) {
        int c = i * 256 + tid;           // 1024 = 128 cols x 8 k8-chunks
        int nn128 = c >> 3, k8 = c & 7;
        f16x8 hi;
#pragma unroll
        for (int e = 0; e < 8; ++e) hi[e] = (_Float16)t[k8 * 8 + e][nn128];
        int gcol = n0 + nn128;
        int strip = gcol >> 11;
        int scol = gcol & 2047;
        size_t p = (size_t)(strip * 128 + (scol >> 6) * 4 + ks4);
        int off = k8 * 1024 + (scol & 63) * 16;
        *(f16x8*)(Bpk + (p << 13) + off) = hi;
    }
    for (int i = 0; i < 32; ++i) {
        int idx = i * 256 + tid;
        int nn = idx >> 6, kk = idx & 63;
        wT[(size_t)(n0 + nn) * DIM + k0 + kk] = t[kk][nn];
    }
}

// ---------------- main: 32x32x16 f16 MFMA, 4 row-waves, ring-4 counted vmcnt ----------------
// grid 1024 flat, XCD-pinned strips. Wave = 32 rows x 64 cols; block 128r x 64c.
// A negated in regs; acc init 0 => acc = -x.w; epilogue adds wnh.
__global__ __launch_bounds__(256, 3)
void vq_mfma(const float* __restrict__ x, const char* __restrict__ Bpk,
             const float* __restrict__ wnh, uint2* __restrict__ part) {
    __shared__ __align__(16) char Bs[4][8192];
    __shared__ float wnhs[2048];

    const int tid = threadIdx.x;
    const int lane = tid & 63;
    const int wid = tid >> 6;
    const int c31 = lane & 31, hi = lane >> 5;
    const int bid = blockIdx.x;
    const int strip = (bid & 7) >> 1;                 // XCD-pair -> strip (bijective)
    const int mblk = (bid >> 3) | ((bid & 1) << 7);

    for (int i = tid; i < 2048; i += 256) wnhs[i] = wnh[strip * 2048 + i];

    // A fragments: -fp16(x); 16 frags (K=256 / 16 per MFMA); k = f*16 + hi*8 + e
    f16x8 a[16];
    {
        const float* xr = x + (size_t)(mblk * 128 + wid * 32 + c31) * DIM + hi * 8;
#pragma unroll
        for (int f = 0; f < 16; ++f) {
            const float* p = xr + f * 16;
            float4 u = *(const float4*)p, v = *(const float4*)(p + 4);
            f16x8 h;
            h[0] = (_Float16)(-u.x); h[1] = (_Float16)(-u.y);
            h[2] = (_Float16)(-u.z); h[3] = (_Float16)(-u.w);
            h[4] = (_Float16)(-v.x); h[5] = (_Float16)(-v.y);
            h[6] = (_Float16)(-v.z); h[7] = (_Float16)(-v.w);
            a[f] = h;
        }
    }

    // packed top-2 keys per row-slot: (mono19(score) & ~0x1FFF) | global_col
    unsigned int v1[16], v2[16];
#pragma unroll
    for (int r = 0; r < 16; ++r) { v1[r] = 0xFFFFFFFFu; v2[r] = 0xFFFFFFFFu; }

    const int t16 = tid << 4;
    const int bbs = hi * 1024 + c31 * 16;   // per-lane ds_read base within panel
    const char* bbase = Bpk + ((size_t)strip << 20);   // 128 panels x 8 KB

    __syncthreads();   // drains wnhs stores + A-build loads; wnhs visible

    // prologue: stage panels 0,1,2 (6 loads outstanding per wave)
#pragma unroll
    for (int p = 0; p < 3; ++p) {
        const char* src = bbase + ((size_t)p << 13);
        GLL(Bs[p] + t16, src + t16);
        GLL(Bs[p] + 4096 + t16, src + 4096 + t16);
    }

    for (int ct = 0; ct < NCT; ++ct) {
        f32x16 acc0, acc1;
#pragma unroll
        for (int e = 0; e < 16; ++e) { acc0[e] = 0.f; acc1[e] = 0.f; }

#pragma unroll
        for (int kp = 0; kp < 4; ++kp) {
            // own panel p = ct*4+kp is the oldest pair of 6 outstanding -> vmcnt(4)
            asm volatile("s_waitcnt vmcnt(4)" ::: "memory");
            __builtin_amdgcn_s_barrier();
            __builtin_amdgcn_sched_barrier(0);
            {   // stage panel p+3 into buf[(kp+3)&3] (its readers all passed this barrier)
                const int pn = (ct * 4 + kp + 3) & 127;   // tail wraps (unread, harmless)
                const char* src = bbase + ((size_t)pn << 13);
                GLL(Bs[(kp + 3) & 3] + t16, src + t16);
                GLL(Bs[(kp + 3) & 3] + 4096 + t16, src + 4096 + t16);
            }
            __builtin_amdgcn_sched_barrier(0);
            __builtin_amdgcn_s_setprio(1);
#pragma unroll
            for (int ks = 0; ks < 4; ++ks) {
                f16x8 b0 = *(const f16x8*)(Bs[kp] + ks * 2048 + bbs);
                f16x8 b1 = *(const f16x8*)(Bs[kp] + ks * 2048 + bbs + 512);
                acc0 = __builtin_amdgcn_mfma_f32_32x32x16_f16(a[kp * 4 + ks], b0, acc0, 0, 0, 0);
                acc1 = __builtin_amdgcn_mfma_f32_32x32x16_f16(a[kp * 4 + ks], b1, acc1, 0, 0, 0);
            }
            __builtin_amdgcn_s_setprio(0);
        }
        // epilogue: score = wnh + acc; fold 32 scores into packed top-2
        {
            const float wv0 = wnhs[ct * 64 + c31];
            const float wv1 = wnhs[ct * 64 + 32 + c31];
            const unsigned int g0 = (unsigned int)(strip * SCOLS + ct * 64 + c31);
            const unsigned int g1 = g0 + 32;
#pragma unroll
            for (int r = 0; r < 16; ++r) {
                float s0 = acc0[r] + wv0;
                float s1 = acc1[r] + wv1;
                unsigned int u0 = __float_as_uint(s0);
                unsigned int k0 = ((u0 ^ ((unsigned int)((int)u0 >> 31) | 0x80000000u))
                                   & 0xFFFFE000u) | g0;
                unsigned int u1 = __float_as_uint(s1);
                unsigned int k1 = ((u1 ^ ((unsigned int)((int)u1 >> 31) | 0x80000000u))
                                   & 0xFFFFE000u) | g1;
                unsigned int nk = min(v1[r], k0);
                v2[r] = min(v2[r], max(v1[r], k0));
                v1[r] = nk;
                nk = min(v1[r], k1);
                v2[r] = min(v2[r], max(v1[r], k1));
                v1[r] = nk;
            }
        }
    }

    // merge across the 32 col-lanes (rows identical within each hi-half)
#pragma unroll
    for (int mask = 1; mask <= 16; mask <<= 1) {
#pragma unroll
        for (int r = 0; r < 16; ++r) {
            unsigned int o1 = (unsigned int)__shfl_xor((int)v1[r], mask);
            unsigned int o2 = (unsigned int)__shfl_xor((int)v2[r], mask);
            unsigned int n2 = min(min(v2[r], o2), max(v1[r], o1));
            v1[r] = min(v1[r], o1);
            v2[r] = n2;
        }
    }
    if (c31 == 0) {   // lanes 0 and 32 each write their hi-half's 16 rows
#pragma unroll
        for (int r = 0; r < 16; ++r) {
            int row = mblk * 128 + wid * 32 + (r & 3) + 8 * (r >> 2) + 4 * hi;
            part[(size_t)strip * N_PTS + row] = make_uint2(v1[r], v2[r]);
        }
    }
}

// ---------------- exact fp64 re-rank of all 8 candidates + gather + loss ----------------
// 256 thr = 4 waves, one row per wave. cand c = lane>>3 (strip c>>1, slot c&1).
__global__ void vq_rerank(const uint2* __restrict__ part, const float* __restrict__ x,
                          const float* __restrict__ wT, int* __restrict__ counts,
                          float* __restrict__ out_idx, float* __restrict__ out_enc,
                          float* __restrict__ outq, float* __restrict__ lossPart) {
    const int lane = threadIdx.x & 63;
    const int row = blockIdx.x * 4 + (threadIdx.x >> 6);
    const int c = lane >> 3;
    uint2 pr = part[(size_t)(c >> 1) * N_PTS + row];
    int idx = (int)(((c & 1) ? pr.y : pr.x) & 0x1FFFu);

    const int d0 = (lane & 7) * 32;
    const float* xp = x + (size_t)row * DIM + d0;
    const float* wp = wT + (size_t)idx * DIM + d0;
    double s = 0.0;
#pragma unroll
    for (int q = 0; q < 8; ++q) {
        float4 xa = *(const float4*)(xp + q * 4);
        float4 wa = *(const float4*)(wp + q * 4);
        double dx;
        dx = (double)xa.x - (double)wa.x; s += dx * dx;
        dx = (double)xa.y - (double)wa.y; s += dx * dx;
        dx = (double)xa.z - (double)wa.z; s += dx * dx;
        dx = (double)xa.w - (double)wa.w; s += dx * dx;
    }
#pragma unroll
    for (int mask = 1; mask <= 4; mask <<= 1) s += __shfl_xor(s, mask);

    double bd = __shfl(s, 0);
    int bi = __shfl(idx, 0);
#pragma unroll
    for (int c2 = 1; c2 < 8; ++c2) {
        double dc = __shfl(s, c2 * 8);
        int ic = __shfl(idx, c2 * 8);
        if (dc < bd || (dc == bd && ic < bi)) { bd = dc; bi = ic; }
    }
    const int best = bi;

    if (lane == 0) {
        out_idx[row] = (float)best;
        out_enc[(size_t)row * K_CODES + best] = 1.0f;  // background stays poison (within threshold)
        atomicAdd(&counts[best], 1);
    }
    // fused gather + loss: lane handles d = lane*4..+4
    float4 xq = *(const float4*)(x + (size_t)row * DIM + lane * 4);
    float4 wq = *(const float4*)(wT + (size_t)best * DIM + lane * 4);
    *(float4*)(outq + (size_t)row * DIM + lane * 4) = wq;
    float d1 = wq.x - xq.x, d2 = wq.y - xq.y, d3 = wq.z - xq.z, d4 = wq.w - xq.w;
    float ls = d1 * d1 + d2 * d2 + d3 * d3 + d4 * d4;

    __shared__ float red[256];
    red[threadIdx.x] = ls;
    __syncthreads();
    for (int m = 128; m > 0; m >>= 1) {
        if (threadIdx.x < m) red[threadIdx.x] += red[threadIdx.x + m];
        __syncthreads();
    }
    if (threadIdx.x == 0) lossPart[blockIdx.x] = red[0];
}

// ---------------- finalize loss + perplexity ----------------
__global__ void vq_final(const int* __restrict__ counts, const float* __restrict__ lossPart,
                         float* __restrict__ out_loss, float* __restrict__ out_perp) {
    __shared__ float red[256];
    __shared__ float red2[256];
    int tid = threadIdx.x;
    float h = 0.f;
    for (int k = tid; k < K_CODES; k += 256) {
        float p = (float)counts[k] * (1.0f / N_PTS);
        h += p * logf(p + 1e-10f);
    }
    float l = 0.f;
    for (int k = tid; k < 8192; k += 256) l += lossPart[k];
    red[tid] = h;
    red2[tid] = l;
    __syncthreads();
    for (int m = 128; m > 0; m >>= 1) {
        if (tid < m) { red[tid] += red[tid + m]; red2[tid] += red2[tid + m]; }
        __syncthreads();
    }
    if (tid == 0) {
        *out_perp = expf(-red[0]);
        *out_loss = 1.25f * red2[0] / 8388608.0f;
    }
}

extern "C" void kernel_launch(void* const* d_in, const int* in_sizes, int n_in,
                              void* d_out, int out_size, void* d_ws, size_t ws_size,
                              hipStream_t stream) {
    const float* x = (const float*)d_in[0];
    const float* w = (const float*)d_in[1];

    float* outf = (float*)d_out;
    float* outq = outf;
    float* out_loss = outf + (size_t)8388608;
    float* out_perp = outf + (size_t)8388609;
    float* out_enc = outf + (size_t)8388610;
    float* out_idx = outf + (size_t)8388610 + (size_t)268435456;

    char* wsb = (char*)d_ws;
    float* wnh = (float*)(wsb + WS_WNH);
    int* counts = (int*)(wsb + WS_COUNTS);
    float* lossPart = (float*)(wsb + WS_LOSSP);
    uint2* part = (uint2*)(wsb + WS_PART);
    float* wT = (float*)(wsb + WS_WT);
    char* Bpk = wsb + WS_BPK;

    vq_prep<<<dim3(32), dim3(256), 0, stream>>>(w, wnh, counts);
    vq_prep_w<<<dim3(256), dim3(256), 0, stream>>>(w, Bpk, wT);

    vq_mfma<<<dim3(1024), dim3(256), 0, stream>>>(x, Bpk, wnh, part);

    vq_rerank<<<dim3(8192), dim3(256), 0, stream>>>(part, x, wT, counts,
                                                    out_idx, out_enc, outq, lossPart);
    vq_final<<<dim3(1), dim3(256), 0, stream>>>(counts, lossPart, out_loss, out_perp);
}